// Round 1
// baseline (1110.402 us; speedup 1.0000x reference)
//
#include <hip/hip_runtime.h>

// ---------- helpers ----------
static __device__ __forceinline__ unsigned short f2bf(float f) {
  union { float f; unsigned u; } v; v.f = f;
  unsigned r = v.u + 0x7fffu + ((v.u >> 16) & 1u);
  return (unsigned short)(r >> 16);
}

struct alignas(8) us4 { unsigned short x, y, z, w; };

typedef __bf16 bf16x8 __attribute__((ext_vector_type(8)));
typedef float f32x4 __attribute__((ext_vector_type(4)));

static __device__ __forceinline__ void load_lds16(const void* g, void* l) {
  __builtin_amdgcn_global_load_lds(
      (const __attribute__((address_space(1))) unsigned int*)g,
      (__attribute__((address_space(3))) unsigned int*)l,
      16, 0, 0);
}

static __device__ __forceinline__ float block_sum(float v, float* sred) {
  #pragma unroll
  for (int o = 32; o > 0; o >>= 1) v += __shfl_down(v, o, 64);
  const int tid = threadIdx.x;
  __syncthreads();
  if ((tid & 63) == 0) sred[tid >> 6] = v;
  __syncthreads();
  return sred[0] + sred[1] + sred[2] + sred[3];
}

// ---------- kernel 1: embedding gather + two RMSNorms -> u (bf16 [4096][1024]) ----------
__global__ __launch_bounds__(256) void embed_norm(
    const int* __restrict__ ids, const float* __restrict__ emb,
    const float* __restrict__ w1, const float* __restrict__ w2,
    unsigned short* __restrict__ u_bf)
{
  __shared__ float sred[4];
  const int row = blockIdx.x;
  const int tid = threadIdx.x;
  const int id = ids[row];
  const float4 e = *(const float4*)(emb + (size_t)id * 1024 + tid * 4);
  float tot = block_sum(e.x*e.x + e.y*e.y + e.z*e.z + e.w*e.w, sred);
  float inv1 = rsqrtf(tot * (1.0f/1024.0f) + 1e-6f);
  const float4 a = *(const float4*)(w1 + tid * 4);
  float x0 = e.x*inv1*a.x, x1 = e.y*inv1*a.y, x2 = e.z*inv1*a.z, x3 = e.w*inv1*a.w;
  float tot2 = block_sum(x0*x0 + x1*x1 + x2*x2 + x3*x3, sred);
  float inv2 = rsqrtf(tot2 * (1.0f/1024.0f) + 1e-6f);
  const float4 b = *(const float4*)(w2 + tid * 4);
  us4 o;
  o.x = f2bf(x0*inv2*b.x); o.y = f2bf(x1*inv2*b.y);
  o.z = f2bf(x2*inv2*b.z); o.w = f2bf(x3*inv2*b.w);
  *(us4*)(u_bf + (size_t)row * 1024 + tid * 4) = o;
}

// ---------- pack kernels: build K-contiguous (transposed) bf16 B-operands ----------
// BcatT [512][1024]: rows 0..255 = B_re columns, 256..511 = B_im columns
__global__ __launch_bounds__(256) void pack_B(
    const float* __restrict__ B_re, const float* __restrict__ B_im,
    unsigned short* __restrict__ BT)
{
  int t = blockIdx.x * 256 + threadIdx.x;    // 512*1024
  int n = t >> 10, k = t & 1023;
  float v = (n < 256) ? B_re[(size_t)k * 256 + n] : B_im[(size_t)k * 256 + (n - 256)];
  BT[t] = f2bf(v);
}

// CcatT [1024][512]: CcatT[d][s] = C_re[s][d] (s<256), = -C_im[s-256][d] (s>=256)
__global__ __launch_bounds__(256) void pack_C(
    const float* __restrict__ C_re, const float* __restrict__ C_im,
    unsigned short* __restrict__ CT)
{
  int t = blockIdx.x * 256 + threadIdx.x;    // 1024*512
  int d = t >> 9, sc = t & 511;
  float v = (sc < 256) ? C_re[(size_t)sc * 1024 + d] : -C_im[(size_t)(sc - 256) * 1024 + d];
  CT[t] = f2bf(v);
}

// head_w fp32 [1024][32000] -> head_wT bf16 [32000][1024] via LDS tile transpose
__global__ __launch_bounds__(256) void transpose_cvt(
    const float* __restrict__ in, unsigned short* __restrict__ out, int Kd, int Nd)
{
  __shared__ float tile[32][33];
  const int n0 = blockIdx.x * 32, k0 = blockIdx.y * 32;
  const int tx = threadIdx.x, ty = threadIdx.y;
  #pragma unroll
  for (int j = 0; j < 32; j += 8)
    tile[ty + j][tx] = in[(size_t)(k0 + ty + j) * Nd + n0 + tx];
  __syncthreads();
  #pragma unroll
  for (int j = 0; j < 32; j += 8)
    out[(size_t)(n0 + ty + j) * Kd + k0 + tx] = f2bf(tile[tx][ty + j]);
}

// ---------- MFMA GEMM: out[M][N] = A[M][K] @ BT[N][K]^T (+bias) ----------
template<bool OUT_BF16, bool HAS_BIAS>
__global__ __launch_bounds__(256) void gemm_bt(
    const unsigned short* __restrict__ A,
    const unsigned short* __restrict__ BT,
    const float* __restrict__ bias,
    void* __restrict__ outp,
    int M, int N, int K)
{
  __shared__ unsigned short As[128 * 32];
  __shared__ unsigned short Bs[128 * 32];
  const int tid = threadIdx.x;
  const int lane = tid & 63;
  const int wave = tid >> 6;
  const int m0 = blockIdx.y * 128;
  const int n0 = blockIdx.x * 128;
  const int wm = (wave >> 1) * 64;
  const int wn = (wave & 1) * 64;

  f32x4 acc[4][4] = {};

  const int lin0 = wave * 64 + lane;       // 0..255
  const int rowS = lin0 >> 2;              // staging row 0..63
  const int koS = (lin0 & 3) * 8;          // k offset 0/8/16/24
  const int aq = lane >> 4;
  const int al = lane & 15;

  for (int k0 = 0; k0 < K; k0 += 32) {
    load_lds16(A  + (size_t)(m0 + rowS)      * K + k0 + koS, As + (size_t)lin0 * 8);
    load_lds16(A  + (size_t)(m0 + 64 + rowS) * K + k0 + koS, As + (size_t)(256 + lin0) * 8);
    load_lds16(BT + (size_t)(n0 + rowS)      * K + k0 + koS, Bs + (size_t)lin0 * 8);
    load_lds16(BT + (size_t)(n0 + 64 + rowS) * K + k0 + koS, Bs + (size_t)(256 + lin0) * 8);
    __syncthreads();
    const bf16x8* Ap = (const bf16x8*)As;
    const bf16x8* Bp = (const bf16x8*)Bs;
    bf16x8 af[4], bfr[4];
    #pragma unroll
    for (int i = 0; i < 4; ++i) af[i] = Ap[(wm + i * 16 + al) * 4 + aq];
    #pragma unroll
    for (int j = 0; j < 4; ++j) bfr[j] = Bp[(wn + j * 16 + al) * 4 + aq];
    #pragma unroll
    for (int i = 0; i < 4; ++i)
      #pragma unroll
      for (int j = 0; j < 4; ++j)
        acc[i][j] = __builtin_amdgcn_mfma_f32_16x16x32_bf16(af[i], bfr[j], acc[i][j], 0, 0, 0);
    __syncthreads();
  }

  const int row0 = m0 + wm + (lane >> 4) * 4;
  const int col0 = n0 + wn + al;
  #pragma unroll
  for (int j = 0; j < 4; ++j) {
    const int col = col0 + j * 16;
    float bv = 0.f;
    if (HAS_BIAS) bv = bias[col];
    #pragma unroll
    for (int i = 0; i < 4; ++i) {
      #pragma unroll
      for (int r = 0; r < 4; ++r) {
        float v = acc[i][j][r] + bv;
        size_t o = (size_t)(row0 + i * 16 + r) * N + col;
        if (OUT_BF16) ((unsigned short*)outp)[o] = f2bf(v);
        else          ((float*)outp)[o] = v;
      }
    }
  }
}

// ---------- scan kernels: xs[l] = A*xs[l-1] + uB[l], chunked (16 chunks of 128) ----------
// uB layout fp32 [4096][512]: re at col s, im at col 256+s. Scan done in place.
__global__ __launch_bounds__(256) void local_scan(
    float* __restrict__ xs, float* __restrict__ carry,
    const float* __restrict__ A_re, const float* __restrict__ A_im)
{
  int t = blockIdx.x * 256 + threadIdx.x;  // 8192 = B(2)*chunks(16)*S(256)
  int s = t & 255;
  int chunk = (t >> 8) & 15;
  int b = t >> 12;
  float ar = A_re[s], ai = A_im[s];
  float xr = 0.f, xi = 0.f;
  size_t base = ((size_t)(b * 2048 + chunk * 128)) * 512 + s;
  for (int j = 0; j < 128; ++j) {
    float ur = xs[base], ui = xs[base + 256];
    float nr = fmaf(ar, xr, fmaf(-ai, xi, ur));
    float ni = fmaf(ar, xi, fmaf(ai, xr, ui));
    xs[base] = nr; xs[base + 256] = ni;
    xr = nr; xi = ni;
    base += 512;
  }
  int ci = (b * 16 + chunk) * 512 + s;
  carry[ci] = xr; carry[ci + 256] = xi;
}

// one block: A-power table (t=0..128) + exclusive carry prefix over chunks
__global__ __launch_bounds__(256) void carry_scan(
    const float* __restrict__ A_re, const float* __restrict__ A_im,
    const float* __restrict__ carry, float* __restrict__ state_before,
    float* __restrict__ Apow)
{
  int s = threadIdx.x;  // 0..255
  float ar = A_re[s], ai = A_im[s];
  float pr = 1.f, pi = 0.f;
  for (int t = 0; t <= 128; ++t) {
    Apow[t * 512 + s] = pr; Apow[t * 512 + 256 + s] = pi;
    float nr = pr * ar - pi * ai;
    float ni = pr * ai + pi * ar;
    pr = nr; pi = ni;
  }
  float cr = Apow[128 * 512 + s], ci = Apow[128 * 512 + 256 + s];  // A^128
  for (int b = 0; b < 2; ++b) {
    float str = 0.f, sti = 0.f;
    for (int c = 0; c < 16; ++c) {
      int idx = (b * 16 + c) * 512 + s;
      state_before[idx] = str; state_before[idx + 256] = sti;
      float lr = carry[idx], li = carry[idx + 256];
      float nr = lr + cr * str - ci * sti;
      float ni = li + cr * sti + ci * str;
      str = nr; sti = ni;
    }
  }
}

// xs_full = xs_local + A^(j+1)*state_before; cast to bf16 (re||im per row)
__global__ __launch_bounds__(256) void combine_cast(
    const float* __restrict__ xs, const float* __restrict__ state_before,
    const float* __restrict__ Apow, unsigned short* __restrict__ xs_cat)
{
  int t = blockIdx.x * 256 + threadIdx.x;  // 4096*256
  int s = t & 255, row = t >> 8;
  int l = row & 2047, b = row >> 11;
  int chunk = l >> 7, j = l & 127;
  size_t o = (size_t)row * 512 + s;
  float xr = xs[o], xi = xs[o + 256];
  int sbi = (b * 16 + chunk) * 512 + s;
  float sr = state_before[sbi], si = state_before[sbi + 256];
  int api = (j + 1) * 512 + s;
  float pr = Apow[api], pi = Apow[api + 256];
  float fr = xr + pr * sr - pi * si;
  float fi = xi + pr * si + pi * sr;
  xs_cat[o] = f2bf(fr); xs_cat[o + 256] = f2bf(fi);
}

// ---------- launch ----------
extern "C" void kernel_launch(void* const* d_in, const int* in_sizes, int n_in,
                              void* d_out, int out_size, void* d_ws, size_t ws_size,
                              hipStream_t stream) {
  (void)in_sizes; (void)n_in; (void)out_size; (void)ws_size;
  const int*   ids    = (const int*)d_in[0];
  const float* emb    = (const float*)d_in[1];
  const float* w1     = (const float*)d_in[2];
  const float* w2     = (const float*)d_in[3];
  const float* A_re   = (const float*)d_in[4];
  const float* A_im   = (const float*)d_in[5];
  const float* B_re   = (const float*)d_in[6];
  const float* B_im   = (const float*)d_in[7];
  const float* C_re   = (const float*)d_in[8];
  const float* C_im   = (const float*)d_in[9];
  const float* D_p    = (const float*)d_in[10];
  const float* head_w = (const float*)d_in[11];
  const float* head_b = (const float*)d_in[12];
  float* out = (float*)d_out;

  // scratch temps live in the front of d_out (dead before the head GEMM
  // overwrites all 524 MB of d_out); persistent-to-the-end buffers in d_ws.
  char* ob = (char*)d_out;
  unsigned short* u_bf   = (unsigned short*)(ob + 0);         //  8,388,608 B
  unsigned short* BcatT  = (unsigned short*)(ob + 8388608);   //  1,048,576 B
  float* uBxs            = (float*)(ob + 9437184);            //  8,388,608 B
  float* carry           = (float*)(ob + 17825792);           //     65,536 B
  float* state_before    = (float*)(ob + 17891328);           //     65,536 B
  float* Apow            = (float*)(ob + 17956864);           //    264,192 B
  unsigned short* xs_cat = (unsigned short*)(ob + 18221056);  //  4,194,304 B
  unsigned short* CcatT  = (unsigned short*)(ob + 22415360);  //  1,048,576 B

  char* wb = (char*)d_ws;
  unsigned short* head_wT = (unsigned short*)(wb + 0);        // 65,536,000 B
  unsigned short* y_bf    = (unsigned short*)(wb + 65536000); //  8,388,608 B

  embed_norm<<<4096, 256, 0, stream>>>(ids, emb, w1, w2, u_bf);
  pack_B<<<2048, 256, 0, stream>>>(B_re, B_im, BcatT);
  pack_C<<<2048, 256, 0, stream>>>(C_re, C_im, CcatT);
  transpose_cvt<<<dim3(1000, 32), dim3(32, 8), 0, stream>>>(head_w, head_wT, 1024, 32000);

  // uB = u @ Bcat   [4096,1024]x[1024,512] -> fp32
  gemm_bt<false, false><<<dim3(4, 32), 256, 0, stream>>>(u_bf, BcatT, nullptr, uBxs, 4096, 512, 1024);

  local_scan<<<32, 256, 0, stream>>>(uBxs, carry, A_re, A_im);
  carry_scan<<<1, 256, 0, stream>>>(A_re, A_im, carry, state_before, Apow);
  combine_cast<<<4096, 256, 0, stream>>>(uBxs, state_before, Apow, xs_cat);

  // y = Re(xs @ C) + D_p   [4096,512]x[512,1024] -> bf16
  gemm_bt<true, true><<<dim3(8, 32), 256, 0, stream>>>(xs_cat, CcatT, D_p, y_bf, 4096, 1024, 512);

  // out = y @ head_w + head_b   [4096,1024]x[1024,32000] -> fp32
  gemm_bt<false, true><<<dim3(250, 32), 256, 0, stream>>>(y_bf, head_wT, head_b, out, 4096, 32000, 1024);
}